// Round 2
// baseline (2603.074 us; speedup 1.0000x reference)
//
#include <hip/hip_runtime.h>
#include <math.h>

#define DC_C 6
#define NRANGE 8          // slot ranges, aligned to blockIdx%8 -> XCD round-robin
#define VCH 2048          // vars per block-chunk in build_b

// Per-check compressed message record (12 B = uint3).
// x = bits(Asp) = sprod*(relu(min2-b)-a)  [value on argmin edges]
// y = bits(Bsp) = sprod*(relu(min1-b)-a)  [value on other edges]
// z = masks: bits 0-5 amin, 8-13 negative-sign, 16-21 zero-sign
// c2v_j = sg_j * (amin_j ? Asp : Bsp), sg_j in {+1,-1,0}.

__device__ __forceinline__ float c2v_from_rec(uint3 r, int j) {
    float val = ((r.z >> j) & 1u) ? __uint_as_float(r.x) : __uint_as_float(r.y);
    float s = ((r.z >> (16 + j)) & 1u) ? 0.0f
            : (((r.z >> (8 + j)) & 1u) ? -1.0f : 1.0f);
    return s * val;
}

// Phase A: slot assignment (nibble-packed counters: 8 checks/word, 4b each).
// Pinned at the device-atomic floor: 1.57M atomics x ~34 B write-through
// = 53 MB at ~940 GB/s = ~61 us. Invariant (R3/R4/R7) — accepted cost.
__global__ void build_a(const int* __restrict__ edge_chk,
                        unsigned int* __restrict__ cnt8,
                        unsigned long long* __restrict__ pos64,
                        int n) {
    int v = blockIdx.x * blockDim.x + threadIdx.x;
    if (v >= n) return;
    int c0 = edge_chk[v * 3 + 0];
    int c1 = edge_chk[v * 3 + 1];
    int c2 = edge_chk[v * 3 + 2];
    unsigned int sh0 = (c0 & 7) * 4, sh1 = (c1 & 7) * 4, sh2 = (c2 & 7) * 4;
    unsigned int o0 = atomicAdd(&cnt8[c0 >> 3], 1u << sh0);
    unsigned int o1 = atomicAdd(&cnt8[c1 >> 3], 1u << sh1);
    unsigned int o2 = atomicAdd(&cnt8[c2 >> 3], 1u << sh2);
    int j0 = (o0 >> sh0) & 0xF;
    int j1 = (o1 >> sh1) & 0xF;
    int j2 = (o2 >> sh2) & 0xF;
    unsigned long long s0 = (unsigned long long)(c0 * DC_C + j0);
    unsigned long long s1 = (unsigned long long)(c1 * DC_C + j1);
    unsigned long long s2 = (unsigned long long)(c2 * DC_C + j2);
    pos64[v] = s0 | (s1 << 21) | (s2 << 42);
}

// Phase B: invert pos64 -> vmap (slot -> variable). Range-partitioned so each
// vmap line is filled from one XCD (blockIdx%8 heuristic; perf-only).
__global__ void build_b(const unsigned long long* __restrict__ pos64,
                        int* __restrict__ vmap,
                        int n, int E) {
    int r = blockIdx.x & (NRANGE - 1);
    int chunk = blockIdx.x >> 3;
    int lo = r * (E / NRANGE);
    int hi = lo + (E / NRANGE);
    int base = chunk * VCH;
#pragma unroll
    for (int rr = 0; rr < VCH / 256; ++rr) {
        int v = base + rr * 256 + threadIdx.x;
        if (v >= n) break;
        unsigned long long pk = pos64[v];
        int s0 = (int)(pk & 0x1FFFFF);
        int s1 = (int)((pk >> 21) & 0x1FFFFF);
        int s2 = (int)((pk >> 42) & 0x1FFFFF);
        if (s0 >= lo && s0 < hi) vmap[s0] = v;
        if (s1 >= lo && s1 < hi) vmap[s1] = v;
        if (s2 >= lo && s2 < hi) vmap[s2] = v;
    }
}

// Monotonic grid barrier for a fully-resident persistent grid.
// Release fetch_add -> buffer_wbl2 + sc1 atomic at LLC (flushes this XCD's
// dirty L2 lines to the coherence point). Acquire spin-load -> sc1 load +
// cache inv (so post-barrier reads miss to LLC and see remote writes).
// This is the same coherence work a dispatch boundary performs, minus the
// command-processor round-trip and wave relaunch.
// Watchdog: if co-residency/coherence assumptions are ever violated, break
// after ~1s instead of hanging the container (fails absmax, keeps counters).
__device__ __forceinline__ void grid_sync(unsigned int* bar, unsigned int target) {
    __syncthreads();
    if (threadIdx.x == 0) {
        __hip_atomic_fetch_add(bar, 1u, __ATOMIC_RELEASE, __HIP_MEMORY_SCOPE_AGENT);
        unsigned int spins = 0;
        while (__hip_atomic_load(bar, __ATOMIC_ACQUIRE, __HIP_MEMORY_SCOPE_AGENT) < target) {
            __builtin_amdgcn_s_sleep(8);
            if (++spins > (1u << 22)) break;   // ~1s watchdog
        }
    }
    __syncthreads();
}

// Persistent fused iteration loop: 1024 blocks x 256 threads. With
// __launch_bounds__(256,4) (VGPR cap 128, LDS 0) all 1024 blocks are
// co-resident on the 256-CU chip (4 blocks/CU) — plain launch, no
// cooperative API. Each thread owns 1 check AND 2 vars (n_chk == n/2 for
// the (3,6)-regular code). Static per-thread data — vmap (6 ints), pos64
// slots (6), llr (2 floats) — loaded ONCE into registers; the check's own
// rec is carried in registers across iterations (no old-rec re-read).
// Per-iteration global traffic is the communication-minimal core:
// 6 p-gathers + rec write (check role), 6 rec-gathers + p write (var role).
__global__ void __launch_bounds__(256, 4)
fused_loop(const float* __restrict__ llr,
           const int* __restrict__ vmap,
           const unsigned long long* __restrict__ pos64,
           uint3* __restrict__ recs,
           float* __restrict__ p,
           const float* __restrict__ beta,
           const float* __restrict__ alpha,
           float* __restrict__ out,
           unsigned int* __restrict__ bar,
           int n, int T, unsigned int nblocks) {
    const int tid = blockIdx.x * blockDim.x + threadIdx.x;  // check id == var-pair id

    // ---- check-role statics ----
    const int cb = tid * DC_C;
    int2 w01 = *(const int2*)(vmap + cb);
    int2 w23 = *(const int2*)(vmap + cb + 2);
    int2 w45 = *(const int2*)(vmap + cb + 4);
    int w[DC_C] = {w01.x, w01.y, w23.x, w23.y, w45.x, w45.y};

    // ---- var-role statics ----
    ulonglong2 pk2 = *(const ulonglong2*)(pos64 + (size_t)tid * 2);
    float2 ll = *(const float2*)(llr + (size_t)tid * 2);
    int s[6] = { (int)(pk2.x & 0x1FFFFF), (int)((pk2.x >> 21) & 0x1FFFFF),
                 (int)((pk2.x >> 42) & 0x1FFFFF),
                 (int)(pk2.y & 0x1FFFFF), (int)((pk2.y >> 21) & 0x1FFFFF),
                 (int)((pk2.y >> 42) & 0x1FFFFF) };
    int ridx[6], rj[6];
#pragma unroll
    for (int k = 0; k < 6; ++k) { ridx[k] = s[k] / DC_C; rj[k] = s[k] % DC_C; }

    uint3 rec = make_uint3(0u, 0u, 0u);
    unsigned int phase = 0;

#pragma unroll 1
    for (int t = 0; t < T; ++t) {
        // ---------- CHECK phase ----------
        const float* src = (t == 0) ? llr : p;   // p_init == llr, c2v_0 == 0
        float pv[DC_C];
#pragma unroll
        for (int j = 0; j < DC_C; ++j) pv[j] = src[w[j]];

        float b = beta[t];
        float a = alpha[t];
        float sprod = 1.0f;
        float m1 = INFINITY, m2 = INFINITY;
        float mg[DC_C];
        unsigned int ng = 0, zr = 0;
#pragma unroll
        for (int j = 0; j < DC_C; ++j) {
            float old_ = (t == 0) ? 0.0f : c2v_from_rec(rec, j);  // reg-carried rec
            float x = pv[j] - old_;
            float m = fabsf(x);
            mg[j] = m;
            if (x < 0.0f) { ng |= (1u << j); sprod = -sprod; }
            else if (x == 0.0f) { zr |= (1u << j); sprod = 0.0f; }
            if (m < m1) { m2 = m1; m1 = m; }
            else if (m < m2) { m2 = m; }
        }
        unsigned int am = 0;
#pragma unroll
        for (int j = 0; j < DC_C; ++j) am |= (mg[j] == m1) ? (1u << j) : 0u;
        // ties: multiple amin bits imply m2==m1 -> A==B, identical to the
        // reference's first-argmin rule.
        float A = fmaxf(m2 - b, 0.0f) - a;
        float B = fmaxf(m1 - b, 0.0f) - a;
        rec = make_uint3(__float_as_uint(sprod * A),
                         __float_as_uint(sprod * B),
                         am | (ng << 8) | (zr << 16));
        recs[tid] = rec;

        grid_sync(bar, (++phase) * nblocks);

        // ---------- VAR / FINAL phase ----------
        uint3 r0 = recs[ridx[0]];
        uint3 r1 = recs[ridx[1]];
        uint3 r2 = recs[ridx[2]];
        uint3 r3 = recs[ridx[3]];
        uint3 r4 = recs[ridx[4]];
        uint3 r5 = recs[ridx[5]];
        float c0 = c2v_from_rec(r0, rj[0]);
        float c1 = c2v_from_rec(r1, rj[1]);
        float c2 = c2v_from_rec(r2, rj[2]);
        float c3 = c2v_from_rec(r3, rj[3]);
        float c4 = c2v_from_rec(r4, rj[4]);
        float c5 = c2v_from_rec(r5, rj[5]);
        float pa = ll.x + ((c0 + c1) + c2);
        float pb = ll.y + ((c3 + c4) + c5);
        if (t + 1 < T) {
            float2 o; o.x = pa; o.y = pb;
            *(float2*)(p + (size_t)tid * 2) = o;
            grid_sync(bar, (++phase) * nblocks);
        } else {
            float2 bits, post;
            bits.x = (pa < 0.0f) ? 1.0f : 0.0f;
            bits.y = (pb < 0.0f) ? 1.0f : 0.0f;
            post.x = pa; post.y = pb;
            *(float2*)(out + (size_t)tid * 2) = bits;
            *(float2*)(out + n + (size_t)tid * 2) = post;
        }
    }
}

extern "C" void kernel_launch(void* const* d_in, const int* in_sizes, int n_in,
                              void* d_out, int out_size, void* d_ws, size_t ws_size,
                              hipStream_t stream) {
    const float* llr      = (const float*)d_in[0];
    const float* beta     = (const float*)d_in[1];
    const float* alpha    = (const float*)d_in[2];
    const int*   edge_chk = (const int*)d_in[4];

    const int n  = in_sizes[0];       // 524288
    const int T  = in_sizes[1];       // 10
    const int E  = in_sizes[3];       // 1572864
    const int n_chk = E / DC_C;       // 262144 == n/2

    // Workspace (rebuilt every call; ws re-poisoned between calls)
    char* ws = (char*)d_ws;
    unsigned int*       cnt8  = (unsigned int*)ws;                      // 128 KB @ 0
    unsigned int*       bar   = (unsigned int*)(ws + (1u << 19));       // 64 B  @ 512K
    unsigned long long* pos64 = (unsigned long long*)(ws + (1u << 20)); // 4 MB @ 1
    int*                vmap  = (int*)(ws + (5u << 20));                // 6 MB @ 5
    uint3*              recs  = (uint3*)(ws + (11u << 20));             // 3 MB @ 11
    float*              p     = (float*)(ws + (14u << 20));             // 2 MB @ 14

    // one memset covers cnt8 (128 KB) and the grid-barrier counter @512K
    hipMemsetAsync(ws, 0, (size_t)(1u << 19) + 64, stream);
    build_a<<<(n + 255) / 256, 256, 0, stream>>>(edge_chk, cnt8, pos64, n);
    {
        int chunks = (n + VCH - 1) / VCH;
        build_b<<<chunks * NRANGE, 256, 0, stream>>>(pos64, vmap, n, E);
    }

    const int nblocks = n_chk / 256;  // 1024 = 4 blocks/CU, all co-resident
    fused_loop<<<nblocks, 256, 0, stream>>>(
        llr, vmap, pos64, (uint3*)recs, p, beta, alpha, (float*)d_out,
        bar, n, T, (unsigned int)nblocks);
}

// Round 3
// 1966.184 us; speedup vs baseline: 1.3239x; 1.3239x over previous
//
#include <hip/hip_runtime.h>
#include <math.h>

#define DC_C 6
#define NRANGE 8          // slot ranges, aligned to blockIdx%8 -> XCD round-robin
#define VCH 2048          // vars per block-chunk in build_b

// Per-check compressed message record (12 B = uint3).
// x = bits(Asp) = sprod*(relu(min2-b)-a)  [value on argmin edges]
// y = bits(Bsp) = sprod*(relu(min1-b)-a)  [value on other edges]
// z = masks: bits 0-5 amin, 8-13 negative-sign, 16-21 zero-sign
// c2v_j = sg_j * (amin_j ? Asp : Bsp), sg_j in {+1,-1,0}.

__device__ __forceinline__ float c2v_from_rec(uint3 r, int j) {
    float val = ((r.z >> j) & 1u) ? __uint_as_float(r.x) : __uint_as_float(r.y);
    float s = ((r.z >> (16 + j)) & 1u) ? 0.0f
            : (((r.z >> (8 + j)) & 1u) ? -1.0f : 1.0f);
    return s * val;
}

// Phase A: slot assignment (nibble-packed counters). Pinned at the
// device-atomic floor (~61 us, R3/R4/R7) — accepted structural cost.
__global__ void build_a(const int* __restrict__ edge_chk,
                        unsigned int* __restrict__ cnt8,
                        unsigned long long* __restrict__ pos64,
                        int n) {
    int v = blockIdx.x * blockDim.x + threadIdx.x;
    if (v >= n) return;
    int c0 = edge_chk[v * 3 + 0];
    int c1 = edge_chk[v * 3 + 1];
    int c2 = edge_chk[v * 3 + 2];
    unsigned int sh0 = (c0 & 7) * 4, sh1 = (c1 & 7) * 4, sh2 = (c2 & 7) * 4;
    unsigned int o0 = atomicAdd(&cnt8[c0 >> 3], 1u << sh0);
    unsigned int o1 = atomicAdd(&cnt8[c1 >> 3], 1u << sh1);
    unsigned int o2 = atomicAdd(&cnt8[c2 >> 3], 1u << sh2);
    int j0 = (o0 >> sh0) & 0xF;
    int j1 = (o1 >> sh1) & 0xF;
    int j2 = (o2 >> sh2) & 0xF;
    unsigned long long s0 = (unsigned long long)(c0 * DC_C + j0);
    unsigned long long s1 = (unsigned long long)(c1 * DC_C + j1);
    unsigned long long s2 = (unsigned long long)(c2 * DC_C + j2);
    pos64[v] = s0 | (s1 << 21) | (s2 << 42);
}

// Phase B: invert pos64 -> vmap (slot -> variable). Range-partitioned so each
// vmap line is filled from one XCD (blockIdx%8 heuristic; perf-only).
__global__ void build_b(const unsigned long long* __restrict__ pos64,
                        int* __restrict__ vmap,
                        int n, int E) {
    int r = blockIdx.x & (NRANGE - 1);
    int chunk = blockIdx.x >> 3;
    int lo = r * (E / NRANGE);
    int hi = lo + (E / NRANGE);
    int base = chunk * VCH;
#pragma unroll
    for (int rr = 0; rr < VCH / 256; ++rr) {
        int v = base + rr * 256 + threadIdx.x;
        if (v >= n) break;
        unsigned long long pk = pos64[v];
        int s0 = (int)(pk & 0x1FFFFF);
        int s1 = (int)((pk >> 21) & 0x1FFFFF);
        int s2 = (int)((pk >> 42) & 0x1FFFFF);
        if (s0 >= lo && s0 < hi) vmap[s0] = v;
        if (s1 >= lo && s1 < hi) vmap[s1] = v;
        if (s2 >= lo && s2 < hi) vmap[s2] = v;
    }
}

// Agent-coherent write-through store (global_store_dword sc1): the line goes
// to the LLC coherence point immediately, so the barrier needs NO buffer_wbl2.
__device__ __forceinline__ void store_wt(unsigned int* a, unsigned int v) {
    __hip_atomic_store(a, v, __ATOMIC_RELAXED, __HIP_MEMORY_SCOPE_AGENT);
}
__device__ __forceinline__ void store_wt_f(float* a, float v) {
    __hip_atomic_store(a, v, __ATOMIC_RELAXED, __HIP_MEMORY_SCOPE_AGENT);
}

// Monotonic grid barrier, dispatch-boundary-equivalent coherence cost:
//  - arrival: s_waitcnt vmcnt(0) (sc1 stores landed at LLC) + RELAXED
//    fetch_add (plain LLC atomic, no cache side effects)
//  - spin:    RELAXED sc1 loads + s_sleep backoff (NO per-poll inv — the
//    per-poll buffer_inv was R2's 8x regression: 0.67% VALUBusy, 200 MB
//    HBM refetch/dispatch from continuous L2 invalidation storms)
//  - exit:    ONE acquire load -> one buffer_inv sc1 per block per barrier
//    (4/CU, same order as a dispatch boundary), so post-barrier plain loads
//    refill L2 fresh and keep intra-phase cross-wave reuse.
// Watchdog bounds the spin (~1s) so a violated assumption fails absmax with
// live counters instead of hanging the container.
__device__ __forceinline__ void grid_sync(unsigned int* bar, unsigned int target) {
    __syncthreads();
    if (threadIdx.x == 0) {
        asm volatile("s_waitcnt vmcnt(0)" ::: "memory");
        __hip_atomic_fetch_add(bar, 1u, __ATOMIC_RELAXED, __HIP_MEMORY_SCOPE_AGENT);
        unsigned int spins = 0;
        while (__hip_atomic_load(bar, __ATOMIC_RELAXED, __HIP_MEMORY_SCOPE_AGENT) < target) {
            __builtin_amdgcn_s_sleep(16);
            if (++spins > (1u << 21)) break;   // ~1s watchdog
        }
        (void)__hip_atomic_load(bar, __ATOMIC_ACQUIRE, __HIP_MEMORY_SCOPE_AGENT);
    }
    __syncthreads();
}

// Persistent fused iteration loop: 1024 blocks x 256 threads. With
// __launch_bounds__(256,4) (VGPR cap 128, LDS 0) all 1024 blocks are
// co-resident on the 256-CU chip (4 blocks/CU) — plain launch. Each thread
// owns 1 check AND 2 vars (n_chk == n/2). Statics (vmap, pos64 slots, llr)
// pinned in registers; the check's own rec is carried in registers across
// iterations. Per-iteration global traffic: 6 p-gathers + 12 B rec
// write-through (check role), 6 rec-gathers + 8 B p write-through (var role).
__global__ void __launch_bounds__(256, 4)
fused_loop(const float* __restrict__ llr,
           const int* __restrict__ vmap,
           const unsigned long long* __restrict__ pos64,
           uint3* __restrict__ recs,
           float* __restrict__ p,
           const float* __restrict__ beta,
           const float* __restrict__ alpha,
           float* __restrict__ out,
           unsigned int* __restrict__ bar,
           int n, int T, unsigned int nblocks) {
    const int tid = blockIdx.x * blockDim.x + threadIdx.x;  // check id == var-pair id

    // ---- check-role statics ----
    const int cb = tid * DC_C;
    int2 w01 = *(const int2*)(vmap + cb);
    int2 w23 = *(const int2*)(vmap + cb + 2);
    int2 w45 = *(const int2*)(vmap + cb + 4);
    int w[DC_C] = {w01.x, w01.y, w23.x, w23.y, w45.x, w45.y};

    // ---- var-role statics ----
    ulonglong2 pk2 = *(const ulonglong2*)(pos64 + (size_t)tid * 2);
    float2 ll = *(const float2*)(llr + (size_t)tid * 2);
    int s[6] = { (int)(pk2.x & 0x1FFFFF), (int)((pk2.x >> 21) & 0x1FFFFF),
                 (int)((pk2.x >> 42) & 0x1FFFFF),
                 (int)(pk2.y & 0x1FFFFF), (int)((pk2.y >> 21) & 0x1FFFFF),
                 (int)((pk2.y >> 42) & 0x1FFFFF) };
    int ridx[6], rj[6];
#pragma unroll
    for (int k = 0; k < 6; ++k) { ridx[k] = s[k] / DC_C; rj[k] = s[k] % DC_C; }

    uint3 rec = make_uint3(0u, 0u, 0u);
    unsigned int phase = 0;

#pragma unroll 1
    for (int t = 0; t < T; ++t) {
        // ---------- CHECK phase ----------
        const float* src = (t == 0) ? llr : p;   // p_init == llr, c2v_0 == 0
        float pv[DC_C];
#pragma unroll
        for (int j = 0; j < DC_C; ++j) pv[j] = src[w[j]];

        float b = beta[t];
        float a = alpha[t];
        float sprod = 1.0f;
        float m1 = INFINITY, m2 = INFINITY;
        float mg[DC_C];
        unsigned int ng = 0, zr = 0;
#pragma unroll
        for (int j = 0; j < DC_C; ++j) {
            float old_ = (t == 0) ? 0.0f : c2v_from_rec(rec, j);  // reg-carried rec
            float x = pv[j] - old_;
            float m = fabsf(x);
            mg[j] = m;
            if (x < 0.0f) { ng |= (1u << j); sprod = -sprod; }
            else if (x == 0.0f) { zr |= (1u << j); sprod = 0.0f; }
            if (m < m1) { m2 = m1; m1 = m; }
            else if (m < m2) { m2 = m; }
        }
        unsigned int am = 0;
#pragma unroll
        for (int j = 0; j < DC_C; ++j) am |= (mg[j] == m1) ? (1u << j) : 0u;
        // ties: multiple amin bits imply m2==m1 -> A==B, identical to the
        // reference's first-argmin rule.
        float A = fmaxf(m2 - b, 0.0f) - a;
        float B = fmaxf(m1 - b, 0.0f) - a;
        rec = make_uint3(__float_as_uint(sprod * A),
                         __float_as_uint(sprod * B),
                         am | (ng << 8) | (zr << 16));
        {   // write-through so the barrier needs no L2 writeback
            unsigned int* rp = (unsigned int*)(recs + tid);
            store_wt(rp + 0, rec.x);
            store_wt(rp + 1, rec.y);
            store_wt(rp + 2, rec.z);
        }

        grid_sync(bar, (++phase) * nblocks);

        // ---------- VAR / FINAL phase ----------
        uint3 r0 = recs[ridx[0]];
        uint3 r1 = recs[ridx[1]];
        uint3 r2 = recs[ridx[2]];
        uint3 r3 = recs[ridx[3]];
        uint3 r4 = recs[ridx[4]];
        uint3 r5 = recs[ridx[5]];
        float c0 = c2v_from_rec(r0, rj[0]);
        float c1 = c2v_from_rec(r1, rj[1]);
        float c2 = c2v_from_rec(r2, rj[2]);
        float c3 = c2v_from_rec(r3, rj[3]);
        float c4 = c2v_from_rec(r4, rj[4]);
        float c5 = c2v_from_rec(r5, rj[5]);
        float pa = ll.x + ((c0 + c1) + c2);
        float pb = ll.y + ((c3 + c4) + c5);
        if (t + 1 < T) {
            store_wt_f(p + (size_t)tid * 2,     pa);
            store_wt_f(p + (size_t)tid * 2 + 1, pb);
            grid_sync(bar, (++phase) * nblocks);
        } else {
            float2 bits, post;
            bits.x = (pa < 0.0f) ? 1.0f : 0.0f;
            bits.y = (pb < 0.0f) ? 1.0f : 0.0f;
            post.x = pa; post.y = pb;
            *(float2*)(out + (size_t)tid * 2) = bits;
            *(float2*)(out + n + (size_t)tid * 2) = post;
        }
    }
}

extern "C" void kernel_launch(void* const* d_in, const int* in_sizes, int n_in,
                              void* d_out, int out_size, void* d_ws, size_t ws_size,
                              hipStream_t stream) {
    const float* llr      = (const float*)d_in[0];
    const float* beta     = (const float*)d_in[1];
    const float* alpha    = (const float*)d_in[2];
    const int*   edge_chk = (const int*)d_in[4];

    const int n  = in_sizes[0];       // 524288
    const int T  = in_sizes[1];       // 10
    const int E  = in_sizes[3];       // 1572864
    const int n_chk = E / DC_C;       // 262144 == n/2

    // Workspace (rebuilt every call; ws re-poisoned between calls)
    char* ws = (char*)d_ws;
    unsigned int*       cnt8  = (unsigned int*)ws;                      // 128 KB @ 0
    unsigned int*       bar   = (unsigned int*)(ws + (1u << 19));       // 64 B  @ 512K
    unsigned long long* pos64 = (unsigned long long*)(ws + (1u << 20)); // 4 MB @ 1
    int*                vmap  = (int*)(ws + (5u << 20));                // 6 MB @ 5
    uint3*              recs  = (uint3*)(ws + (11u << 20));             // 3 MB @ 11
    float*              p     = (float*)(ws + (14u << 20));             // 2 MB @ 14

    // one memset covers cnt8 (128 KB) and the grid-barrier counter @512K
    hipMemsetAsync(ws, 0, (size_t)(1u << 19) + 64, stream);
    build_a<<<(n + 255) / 256, 256, 0, stream>>>(edge_chk, cnt8, pos64, n);
    {
        int chunks = (n + VCH - 1) / VCH;
        build_b<<<chunks * NRANGE, 256, 0, stream>>>(pos64, vmap, n, E);
    }

    const int nblocks = n_chk / 256;  // 1024 = 4 blocks/CU, all co-resident
    fused_loop<<<nblocks, 256, 0, stream>>>(
        llr, vmap, pos64, (uint3*)recs, p, beta, alpha, (float*)d_out,
        bar, n, T, (unsigned int)nblocks);
}

// Round 4
// 482.039 us; speedup vs baseline: 5.4001x; 4.0789x over previous
//
#include <hip/hip_runtime.h>
#include <math.h>

#define DC_C 6
#define NRANGE 8          // slot ranges, aligned to blockIdx%8 -> XCD round-robin
#define VCH 2048          // vars per block-chunk in init_v2c

// Per-check compressed message record (12 B = uint3).
// x = bits(Asp) = sprod*(relu(min2-b)-a)  [value on argmin edges]
// y = bits(Bsp) = sprod*(relu(min1-b)-a)  [value on other edges]
// z = masks: bits 0-5 amin, 8-13 negative-sign, 16-21 zero-sign
// c2v_j = sg_j * (amin_j ? Asp : Bsp), sg_j in {+1,-1,0}.
//
// v2c-slot formulation (this round): v2c[slot] = p - c2v_old is maintained
// per-EDGE by var_kernel (scatter), so check_kernel reads its 6 inputs
// CONTIGUOUSLY (slot = c*6+j) — zero gathers, no vmap, no old-rec subtract.
// The gather cost lives only in var (6 rec-gathers from the 3 MB recs array,
// the smallest possible gather target). Same float ops in the same order as
// the verified R0 kernel -> bit-exact.

__device__ __forceinline__ float c2v_from_rec(uint3 r, int j) {
    float val = ((r.z >> j) & 1u) ? __uint_as_float(r.x) : __uint_as_float(r.y);
    float s = ((r.z >> (16 + j)) & 1u) ? 0.0f
            : (((r.z >> (8 + j)) & 1u) ? -1.0f : 1.0f);
    return s * val;
}

__device__ __forceinline__ uint3 make_rec(const float pv[DC_C], float b, float a) {
    float sprod = 1.0f;
    float m1 = INFINITY, m2 = INFINITY;
    float mg[DC_C];
    unsigned int ng = 0, zr = 0;
#pragma unroll
    for (int j = 0; j < DC_C; ++j) {
        float x = pv[j];
        float m = fabsf(x);
        mg[j] = m;
        if (x < 0.0f) { ng |= (1u << j); sprod = -sprod; }
        else if (x == 0.0f) { zr |= (1u << j); sprod = 0.0f; }
        if (m < m1) { m2 = m1; m1 = m; }
        else if (m < m2) { m2 = m; }
    }
    unsigned int am = 0;
#pragma unroll
    for (int j = 0; j < DC_C; ++j) am |= (mg[j] == m1) ? (1u << j) : 0u;
    // ties: multiple amin bits imply m2==m1 -> A==B, identical to the
    // reference's first-argmin rule.
    float A = fmaxf(m2 - b, 0.0f) - a;
    float B = fmaxf(m1 - b, 0.0f) - a;
    return make_uint3(__float_as_uint(sprod * A),
                      __float_as_uint(sprod * B),
                      am | (ng << 8) | (zr << 16));
}

// Phase A: slot assignment (nibble-packed counters). Pinned at the
// device-atomic floor (~61 us, R3/R4/R7) — accepted structural cost.
__global__ void build_a(const int* __restrict__ edge_chk,
                        unsigned int* __restrict__ cnt8,
                        unsigned long long* __restrict__ pos64,
                        int n) {
    int v = blockIdx.x * blockDim.x + threadIdx.x;
    if (v >= n) return;
    int c0 = edge_chk[v * 3 + 0];
    int c1 = edge_chk[v * 3 + 1];
    int c2 = edge_chk[v * 3 + 2];
    unsigned int sh0 = (c0 & 7) * 4, sh1 = (c1 & 7) * 4, sh2 = (c2 & 7) * 4;
    unsigned int o0 = atomicAdd(&cnt8[c0 >> 3], 1u << sh0);
    unsigned int o1 = atomicAdd(&cnt8[c1 >> 3], 1u << sh1);
    unsigned int o2 = atomicAdd(&cnt8[c2 >> 3], 1u << sh2);
    int j0 = (o0 >> sh0) & 0xF;
    int j1 = (o1 >> sh1) & 0xF;
    int j2 = (o2 >> sh2) & 0xF;
    unsigned long long s0 = (unsigned long long)(c0 * DC_C + j0);
    unsigned long long s1 = (unsigned long long)(c1 * DC_C + j1);
    unsigned long long s2 = (unsigned long long)(c2 * DC_C + j2);
    pos64[v] = s0 | (s1 << 21) | (s2 << 42);
}

// Phase B (replaces build_b): initialize v2c[slot] = llr[var]. Same
// range-partitioned scatter structure as the old vmap build (XCD-locality
// heuristic, perf-only). No vmap exists anymore.
__global__ void init_v2c(const unsigned long long* __restrict__ pos64,
                         const float* __restrict__ llr,
                         float* __restrict__ v2c,
                         int n, int E) {
    int r = blockIdx.x & (NRANGE - 1);
    int chunk = blockIdx.x >> 3;
    int lo = r * (E / NRANGE);
    int hi = lo + (E / NRANGE);
    int base = chunk * VCH;
#pragma unroll
    for (int rr = 0; rr < VCH / 256; ++rr) {
        int v = base + rr * 256 + threadIdx.x;
        if (v >= n) break;
        unsigned long long pk = pos64[v];
        float lv = llr[v];
        int s0 = (int)(pk & 0x1FFFFF);
        int s1 = (int)((pk >> 21) & 0x1FFFFF);
        int s2 = (int)((pk >> 42) & 0x1FFFFF);
        if (s0 >= lo && s0 < hi) v2c[s0] = lv;
        if (s1 >= lo && s1 < hi) v2c[s1] = lv;
        if (s2 >= lo && s2 < hi) v2c[s2] = lv;
    }
}

// Check-node update, 2 checks/thread, PURE STREAMING: reads 12 contiguous
// v2c floats (3x float4, 48B/thread), writes 2 recs (3x uint2, 24B/thread).
// Zero gathers, zero vmap, zero old-rec subtraction.
__global__ void check_kernel(const float* __restrict__ v2c,
                             unsigned int* __restrict__ recs_u,
                             const float* __restrict__ beta,
                             const float* __restrict__ alpha,
                             int t, int npair) {
    int i = blockIdx.x * blockDim.x + threadIdx.x;
    if (i >= npair) return;
    const float4* vb = (const float4*)(v2c + (size_t)i * 12);
    float4 q0 = vb[0];
    float4 q1 = vb[1];
    float4 q2 = vb[2];
    float b = beta[t];
    float a = alpha[t];
    float pv0[DC_C] = {q0.x, q0.y, q0.z, q0.w, q1.x, q1.y};
    float pv1[DC_C] = {q1.z, q1.w, q2.x, q2.y, q2.z, q2.w};
    uint3 r0 = make_rec(pv0, b, a);
    uint3 r1 = make_rec(pv1, b, a);
    uint2* rb = (uint2*)(recs_u + (size_t)i * 6);   // 24B-aligned base
    rb[0] = make_uint2(r0.x, r0.y);
    rb[1] = make_uint2(r0.z, r1.x);
    rb[2] = make_uint2(r1.y, r1.z);
}

// Variable-node update, 2 vars/thread (measured optimum).
// Coalesced: pos64 (ulonglong2), llr (float2). Random: 6 rec-gathers from
// the 3 MB L2/LLC-resident recs array; 6 x 4B v2c scatter-writes.
// v2c[slot] = p - c2v  (identical op order to the verified R0 kernel).
__global__ void var_kernel(const uint3* __restrict__ recs,
                           const unsigned long long* __restrict__ pos64,
                           const float* __restrict__ llr,
                           float* __restrict__ v2c,
                           int n2) {       // n/2
    int i = blockIdx.x * blockDim.x + threadIdx.x;
    if (i >= n2) return;
    ulonglong2 pk2 = *(const ulonglong2*)(pos64 + (size_t)i * 2);
    float2 ll = *(const float2*)(llr + (size_t)i * 2);
    int a0 = (int)(pk2.x & 0x1FFFFF);
    int a1 = (int)((pk2.x >> 21) & 0x1FFFFF);
    int a2 = (int)((pk2.x >> 42) & 0x1FFFFF);
    int b0 = (int)(pk2.y & 0x1FFFFF);
    int b1 = (int)((pk2.y >> 21) & 0x1FFFFF);
    int b2 = (int)((pk2.y >> 42) & 0x1FFFFF);
    uint3 ra0 = recs[a0 / DC_C];
    uint3 ra1 = recs[a1 / DC_C];
    uint3 ra2 = recs[a2 / DC_C];
    uint3 rb0 = recs[b0 / DC_C];
    uint3 rb1 = recs[b1 / DC_C];
    uint3 rb2 = recs[b2 / DC_C];
    float ca0 = c2v_from_rec(ra0, a0 % DC_C);
    float ca1 = c2v_from_rec(ra1, a1 % DC_C);
    float ca2 = c2v_from_rec(ra2, a2 % DC_C);
    float cb0 = c2v_from_rec(rb0, b0 % DC_C);
    float cb1 = c2v_from_rec(rb1, b1 % DC_C);
    float cb2 = c2v_from_rec(rb2, b2 % DC_C);
    float pa = ll.x + ((ca0 + ca1) + ca2);
    float pb = ll.y + ((cb0 + cb1) + cb2);
    v2c[a0] = pa - ca0;
    v2c[a1] = pa - ca1;
    v2c[a2] = pa - ca2;
    v2c[b0] = pb - cb0;
    v2c[b1] = pb - cb1;
    v2c[b2] = pb - cb2;
}

// Final: posterior + hard decision, 2 vars/thread.
// out[0..n)=bits(f32 0/1), out[n..2n)=posterior.
__global__ void final_kernel(const uint3* __restrict__ recs,
                             const unsigned long long* __restrict__ pos64,
                             const float* __restrict__ llr,
                             float* __restrict__ out,
                             int n2, int n) {
    int i = blockIdx.x * blockDim.x + threadIdx.x;
    if (i >= n2) return;
    ulonglong2 pk2 = *(const ulonglong2*)(pos64 + (size_t)i * 2);
    float2 ll = *(const float2*)(llr + (size_t)i * 2);
    int a0 = (int)(pk2.x & 0x1FFFFF);
    int a1 = (int)((pk2.x >> 21) & 0x1FFFFF);
    int a2 = (int)((pk2.x >> 42) & 0x1FFFFF);
    int b0 = (int)(pk2.y & 0x1FFFFF);
    int b1 = (int)((pk2.y >> 21) & 0x1FFFFF);
    int b2 = (int)((pk2.y >> 42) & 0x1FFFFF);
    uint3 ra0 = recs[a0 / DC_C];
    uint3 ra1 = recs[a1 / DC_C];
    uint3 ra2 = recs[a2 / DC_C];
    uint3 rb0 = recs[b0 / DC_C];
    uint3 rb1 = recs[b1 / DC_C];
    uint3 rb2 = recs[b2 / DC_C];
    float pa = ll.x + ((c2v_from_rec(ra0, a0 % DC_C)
                      + c2v_from_rec(ra1, a1 % DC_C))
                      + c2v_from_rec(ra2, a2 % DC_C));
    float pb = ll.y + ((c2v_from_rec(rb0, b0 % DC_C)
                      + c2v_from_rec(rb1, b1 % DC_C))
                      + c2v_from_rec(rb2, b2 % DC_C));
    float2 bits, post;
    bits.x = (pa < 0.0f) ? 1.0f : 0.0f;
    bits.y = (pb < 0.0f) ? 1.0f : 0.0f;
    post.x = pa;
    post.y = pb;
    *(float2*)(out + (size_t)i * 2) = bits;
    *(float2*)(out + n + (size_t)i * 2) = post;
}

extern "C" void kernel_launch(void* const* d_in, const int* in_sizes, int n_in,
                              void* d_out, int out_size, void* d_ws, size_t ws_size,
                              hipStream_t stream) {
    const float* llr      = (const float*)d_in[0];
    const float* beta     = (const float*)d_in[1];
    const float* alpha    = (const float*)d_in[2];
    const int*   edge_chk = (const int*)d_in[4];

    const int n  = in_sizes[0];       // 524288
    const int T  = in_sizes[1];       // 10
    const int E  = in_sizes[3];       // 1572864
    const int n_chk = E / DC_C;       // 262144

    // Workspace (rebuilt every call; ws re-poisoned between calls)
    char* ws = (char*)d_ws;
    unsigned int*       cnt8  = (unsigned int*)ws;                      // 128 KB @ 0
    unsigned long long* pos64 = (unsigned long long*)(ws + (1u << 20)); // 4 MB @ 1
    float*              v2c   = (float*)(ws + (5u << 20));              // 6 MB @ 5
    unsigned int*       recs  = (unsigned int*)(ws + (11u << 20));      // 3 MB @ 11

    hipMemsetAsync(cnt8, 0, (size_t)(n_chk / 8) * 4, stream);
    build_a<<<(n + 255) / 256, 256, 0, stream>>>(edge_chk, cnt8, pos64, n);
    {
        int chunks = (n + VCH - 1) / VCH;
        init_v2c<<<chunks * NRANGE, 256, 0, stream>>>(pos64, llr, v2c, n, E);
    }
    const int npair = n_chk / 2;      // 131072 check-pairs
    for (int t = 0; t < T; ++t) {
        check_kernel<<<(npair + 255) / 256, 256, 0, stream>>>(
            v2c, recs, beta, alpha, t, npair);
        if (t + 1 < T) {
            var_kernel<<<(n / 2 + 255) / 256, 256, 0, stream>>>(
                (const uint3*)recs, pos64, llr, v2c, n / 2);
        } else {
            final_kernel<<<(n / 2 + 255) / 256, 256, 0, stream>>>(
                (const uint3*)recs, pos64, llr, (float*)d_out, n / 2, n);
        }
    }
}

// Round 5
// 437.656 us; speedup vs baseline: 5.9478x; 1.1014x over previous
//
#include <hip/hip_runtime.h>
#include <math.h>

#define DC_C 6
#define NRANGE 8          // slot ranges, aligned to blockIdx%8 -> XCD round-robin
#define VCH 2048          // vars per block-chunk in scatter-build kernels

// Per-check compressed message record (12 B = uint3).
// x = bits(Asp) = sprod*(relu(min2-b)-a)  [value on argmin edges]
// y = bits(Bsp) = sprod*(relu(min1-b)-a)  [value on other edges]
// z = masks: bits 0-5 amin, 8-13 negative-sign, 16-21 zero-sign
// c2v_j = sg_j * (amin_j ? Asp : Bsp), sg_j in {+1,-1,0}.
//
// R4 lesson: random READS are cheap (read-shared, L2-replicated); random
// WRITES are poison (partial-line dirty merges across 8 non-coherent L2s).
// This round: barrier-free check+var fusion. v2c_j = (llr_v+((e0+e1)+e2))-eS
// needs only the var's 2 SIBLING recs (gather) + own old rec (coalesced).
// recs double-buffered (read t-1, write t) -> no intra-dispatch race.
// Iteration = ONE dispatch; p array eliminated; all writes coalesced;
// gather count per iteration identical to the split structure.

__device__ __forceinline__ float c2v_from_rec(uint3 r, int j) {
    float val = ((r.z >> j) & 1u) ? __uint_as_float(r.x) : __uint_as_float(r.y);
    float s = ((r.z >> (16 + j)) & 1u) ? 0.0f
            : (((r.z >> (8 + j)) & 1u) ? -1.0f : 1.0f);
    return s * val;
}

__device__ __forceinline__ uint3 make_rec(const float pv[DC_C], float b, float a) {
    float sprod = 1.0f;
    float m1 = INFINITY, m2 = INFINITY;
    float mg[DC_C];
    unsigned int ng = 0, zr = 0;
#pragma unroll
    for (int j = 0; j < DC_C; ++j) {
        float x = pv[j];
        float m = fabsf(x);
        mg[j] = m;
        if (x < 0.0f) { ng |= (1u << j); sprod = -sprod; }
        else if (x == 0.0f) { zr |= (1u << j); sprod = 0.0f; }
        if (m < m1) { m2 = m1; m1 = m; }
        else if (m < m2) { m2 = m; }
    }
    unsigned int am = 0;
#pragma unroll
    for (int j = 0; j < DC_C; ++j) am |= (mg[j] == m1) ? (1u << j) : 0u;
    // ties: multiple amin bits imply m2==m1 -> A==B, identical to the
    // reference's first-argmin rule.
    float A = fmaxf(m2 - b, 0.0f) - a;
    float B = fmaxf(m1 - b, 0.0f) - a;
    return make_uint3(__float_as_uint(sprod * A),
                      __float_as_uint(sprod * B),
                      am | (ng << 8) | (zr << 16));
}

// Phase A: slot assignment (nibble-packed counters). Pinned at the
// device-atomic floor (~61 us) — accepted structural cost.
__global__ void build_a(const int* __restrict__ edge_chk,
                        unsigned int* __restrict__ cnt8,
                        unsigned long long* __restrict__ pos64,
                        int n) {
    int v = blockIdx.x * blockDim.x + threadIdx.x;
    if (v >= n) return;
    int c0 = edge_chk[v * 3 + 0];
    int c1 = edge_chk[v * 3 + 1];
    int c2 = edge_chk[v * 3 + 2];
    unsigned int sh0 = (c0 & 7) * 4, sh1 = (c1 & 7) * 4, sh2 = (c2 & 7) * 4;
    unsigned int o0 = atomicAdd(&cnt8[c0 >> 3], 1u << sh0);
    unsigned int o1 = atomicAdd(&cnt8[c1 >> 3], 1u << sh1);
    unsigned int o2 = atomicAdd(&cnt8[c2 >> 3], 1u << sh2);
    int j0 = (o0 >> sh0) & 0xF;
    int j1 = (o1 >> sh1) & 0xF;
    int j2 = (o2 >> sh2) & 0xF;
    unsigned long long s0 = (unsigned long long)(c0 * DC_C + j0);
    unsigned long long s1 = (unsigned long long)(c1 * DC_C + j1);
    unsigned long long s2 = (unsigned long long)(c2 * DC_C + j2);
    pos64[v] = s0 | (s1 << 21) | (s2 << 42);
}

// Build the per-slot static table: stat[slot] packs
//   [0,21)  sibling-A ref = (chk<<3)|lane   (first sibling in EDGE order)
//   [21,42) sibling-B ref = (chk<<3)|lane   (second sibling in EDGE order)
//   [42,44) k = self position among the var's 3 edges (edge order)
//   [44,64) var id
// Range-partitioned by CHECK id for scatter locality (one-time cost).
__global__ void build_stat(const unsigned long long* __restrict__ pos64,
                           unsigned long long* __restrict__ stat,
                           int n, int n_chk) {
    int r = blockIdx.x & (NRANGE - 1);
    int chunk = blockIdx.x >> 3;
    int lo = r * (n_chk / NRANGE);
    int hi = lo + (n_chk / NRANGE);
    int base = chunk * VCH;
#pragma unroll
    for (int rr = 0; rr < VCH / 256; ++rr) {
        int v = base + rr * 256 + threadIdx.x;
        if (v >= n) break;
        unsigned long long pk = pos64[v];
        int s0 = (int)(pk & 0x1FFFFF);
        int s1 = (int)((pk >> 21) & 0x1FFFFF);
        int s2 = (int)((pk >> 42) & 0x1FFFFF);
        int c0 = s0 / DC_C, c1 = s1 / DC_C, c2 = s2 / DC_C;
        unsigned long long p0 = ((unsigned long long)c0 << 3) | (unsigned)(s0 - c0 * DC_C);
        unsigned long long p1 = ((unsigned long long)c1 << 3) | (unsigned)(s1 - c1 * DC_C);
        unsigned long long p2 = ((unsigned long long)c2 << 3) | (unsigned)(s2 - c2 * DC_C);
        unsigned long long vv = (unsigned long long)v << 44;
        if (c0 >= lo && c0 < hi)
            stat[s0] = p1 | (p2 << 21) | (0ull << 42) | vv;
        if (c1 >= lo && c1 < hi)
            stat[s1] = p0 | (p2 << 21) | (1ull << 42) | vv;
        if (c2 >= lo && c2 < hi)
            stat[s2] = p0 | (p1 << 21) | (2ull << 42) | vv;
    }
}

// Fused var+check iteration, 1 check/thread, barrier-free via rec
// double-buffer. Coalesced: stat (3x ulonglong2, 48B), own old rec, new rec
// write. Random READS only: 12 sibling-rec gathers (3 MB target) + 6 llr
// gathers (2 MB target). Identical FP expression/order to the verified
// split pipeline: p = llr + ((e0+e1)+e2) in edge order; v2c = p - e_self.
__global__ void __launch_bounds__(256, 4)
fused_check(const unsigned long long* __restrict__ stat,
            const float* __restrict__ llr,
            const uint3* __restrict__ rd,     // recs at t-1
            uint3* __restrict__ wr,           // recs at t
            const float* __restrict__ beta,
            const float* __restrict__ alpha,
            int t, int n_chk, int first) {
    int c = blockIdx.x * blockDim.x + threadIdx.x;
    if (c >= n_chk) return;
    const ulonglong2* sb = (const ulonglong2*)(stat + (size_t)c * DC_C);
    ulonglong2 q0 = sb[0];
    ulonglong2 q1 = sb[1];
    ulonglong2 q2 = sb[2];
    unsigned long long sv[DC_C] = {q0.x, q0.y, q1.x, q1.y, q2.x, q2.y};
    float b = beta[t];
    float a = alpha[t];
    float pv[DC_C];
    if (first) {
        // v2c_0 = llr (c2v_0 == 0), identical to reference init
#pragma unroll
        for (int j = 0; j < DC_C; ++j)
            pv[j] = llr[(int)(sv[j] >> 44)];
    } else {
        uint3 ro = rd[c];
#pragma unroll
        for (int j = 0; j < DC_C; ++j) {
            unsigned int ra = (unsigned int)(sv[j] & 0x1FFFFF);
            unsigned int rb = (unsigned int)((sv[j] >> 21) & 0x1FFFFF);
            int k = (int)((sv[j] >> 42) & 3);
            int vtx = (int)(sv[j] >> 44);
            uint3 rA = rd[ra >> 3];
            uint3 rB = rd[rb >> 3];
            float cA = c2v_from_rec(rA, (int)(ra & 7));
            float cB = c2v_from_rec(rB, (int)(rb & 7));
            float cS = c2v_from_rec(ro, j);
            // place self among siblings in EDGE order (siblings stored in
            // edge order): k=0 -> (S,A,B); k=1 -> (A,S,B); k=2 -> (A,B,S)
            float e0 = (k == 0) ? cS : cA;
            float e1 = (k == 0) ? cA : ((k == 1) ? cS : cB);
            float e2 = (k == 2) ? cS : cB;
            float p = llr[vtx] + ((e0 + e1) + e2);
            pv[j] = p - cS;
        }
    }
    wr[c] = make_rec(pv, b, a);
}

// Final: posterior + hard decision, 2 vars/thread (verified R0 kernel).
// out[0..n)=bits(f32 0/1), out[n..2n)=posterior.
__global__ void final_kernel(const uint3* __restrict__ recs,
                             const unsigned long long* __restrict__ pos64,
                             const float* __restrict__ llr,
                             float* __restrict__ out,
                             int n2, int n) {
    int i = blockIdx.x * blockDim.x + threadIdx.x;
    if (i >= n2) return;
    ulonglong2 pk2 = *(const ulonglong2*)(pos64 + (size_t)i * 2);
    float2 ll = *(const float2*)(llr + (size_t)i * 2);
    int a0 = (int)(pk2.x & 0x1FFFFF);
    int a1 = (int)((pk2.x >> 21) & 0x1FFFFF);
    int a2 = (int)((pk2.x >> 42) & 0x1FFFFF);
    int b0 = (int)(pk2.y & 0x1FFFFF);
    int b1 = (int)((pk2.y >> 21) & 0x1FFFFF);
    int b2 = (int)((pk2.y >> 42) & 0x1FFFFF);
    uint3 ra0 = recs[a0 / DC_C];
    uint3 ra1 = recs[a1 / DC_C];
    uint3 ra2 = recs[a2 / DC_C];
    uint3 rb0 = recs[b0 / DC_C];
    uint3 rb1 = recs[b1 / DC_C];
    uint3 rb2 = recs[b2 / DC_C];
    float pa = ll.x + ((c2v_from_rec(ra0, a0 % DC_C)
                      + c2v_from_rec(ra1, a1 % DC_C))
                      + c2v_from_rec(ra2, a2 % DC_C));
    float pb = ll.y + ((c2v_from_rec(rb0, b0 % DC_C)
                      + c2v_from_rec(rb1, b1 % DC_C))
                      + c2v_from_rec(rb2, b2 % DC_C));
    float2 bits, post;
    bits.x = (pa < 0.0f) ? 1.0f : 0.0f;
    bits.y = (pb < 0.0f) ? 1.0f : 0.0f;
    post.x = pa;
    post.y = pb;
    *(float2*)(out + (size_t)i * 2) = bits;
    *(float2*)(out + n + (size_t)i * 2) = post;
}

// ---------- fallback path (verified R0 pipeline, 16 MB footprint) ----------
__global__ void build_b(const unsigned long long* __restrict__ pos64,
                        int* __restrict__ vmap,
                        int n, int E) {
    int r = blockIdx.x & (NRANGE - 1);
    int chunk = blockIdx.x >> 3;
    int lo = r * (E / NRANGE);
    int hi = lo + (E / NRANGE);
    int base = chunk * VCH;
#pragma unroll
    for (int rr = 0; rr < VCH / 256; ++rr) {
        int v = base + rr * 256 + threadIdx.x;
        if (v >= n) break;
        unsigned long long pk = pos64[v];
        int s0 = (int)(pk & 0x1FFFFF);
        int s1 = (int)((pk >> 21) & 0x1FFFFF);
        int s2 = (int)((pk >> 42) & 0x1FFFFF);
        if (s0 >= lo && s0 < hi) vmap[s0] = v;
        if (s1 >= lo && s1 < hi) vmap[s1] = v;
        if (s2 >= lo && s2 < hi) vmap[s2] = v;
    }
}

__global__ void check_kernel(const float* __restrict__ p,
                             const int* __restrict__ vmap,
                             uint3* __restrict__ recs,
                             const float* __restrict__ beta,
                             const float* __restrict__ alpha,
                             int t, int n_chk, int first) {
    int c = blockIdx.x * blockDim.x + threadIdx.x;
    if (c >= n_chk) return;
    int base = c * DC_C;
    int2 w01 = *(const int2*)(vmap + base);
    int2 w23 = *(const int2*)(vmap + base + 2);
    int2 w45 = *(const int2*)(vmap + base + 4);
    int w[DC_C] = {w01.x, w01.y, w23.x, w23.y, w45.x, w45.y};
    float pvv[DC_C];
#pragma unroll
    for (int j = 0; j < DC_C; ++j) pvv[j] = p[w[j]];
    float old_[DC_C];
    if (first) {
#pragma unroll
        for (int j = 0; j < DC_C; ++j) old_[j] = 0.0f;
    } else {
        uint3 rec = recs[c];
#pragma unroll
        for (int j = 0; j < DC_C; ++j) old_[j] = c2v_from_rec(rec, j);
    }
    float pv[DC_C];
#pragma unroll
    for (int j = 0; j < DC_C; ++j) pv[j] = pvv[j] - old_[j];
    recs[c] = make_rec(pv, beta[t], alpha[t]);
}

__global__ void var_kernel(const uint3* __restrict__ recs,
                           const unsigned long long* __restrict__ pos64,
                           const float* __restrict__ llr,
                           float* __restrict__ p,
                           int n2) {
    int i = blockIdx.x * blockDim.x + threadIdx.x;
    if (i >= n2) return;
    ulonglong2 pk2 = *(const ulonglong2*)(pos64 + (size_t)i * 2);
    float2 ll = *(const float2*)(llr + (size_t)i * 2);
    int a0 = (int)(pk2.x & 0x1FFFFF);
    int a1 = (int)((pk2.x >> 21) & 0x1FFFFF);
    int a2 = (int)((pk2.x >> 42) & 0x1FFFFF);
    int b0 = (int)(pk2.y & 0x1FFFFF);
    int b1 = (int)((pk2.y >> 21) & 0x1FFFFF);
    int b2 = (int)((pk2.y >> 42) & 0x1FFFFF);
    uint3 ra0 = recs[a0 / DC_C];
    uint3 ra1 = recs[a1 / DC_C];
    uint3 ra2 = recs[a2 / DC_C];
    uint3 rb0 = recs[b0 / DC_C];
    uint3 rb1 = recs[b1 / DC_C];
    uint3 rb2 = recs[b2 / DC_C];
    float2 o;
    o.x = ll.x + ((c2v_from_rec(ra0, a0 % DC_C)
                 + c2v_from_rec(ra1, a1 % DC_C))
                 + c2v_from_rec(ra2, a2 % DC_C));
    o.y = ll.y + ((c2v_from_rec(rb0, b0 % DC_C)
                 + c2v_from_rec(rb1, b1 % DC_C))
                 + c2v_from_rec(rb2, b2 % DC_C));
    *(float2*)(p + (size_t)i * 2) = o;
}

extern "C" void kernel_launch(void* const* d_in, const int* in_sizes, int n_in,
                              void* d_out, int out_size, void* d_ws, size_t ws_size,
                              hipStream_t stream) {
    const float* llr      = (const float*)d_in[0];
    const float* beta     = (const float*)d_in[1];
    const float* alpha    = (const float*)d_in[2];
    const int*   edge_chk = (const int*)d_in[4];

    const int n  = in_sizes[0];       // 524288
    const int T  = in_sizes[1];       // 10
    const int E  = in_sizes[3];       // 1572864
    const int n_chk = E / DC_C;       // 262144

    char* ws = (char*)d_ws;
    const int chunks = (n + VCH - 1) / VCH;

    if (ws_size >= ((size_t)24 << 20)) {
        // ---- fused pipeline (24 MB) ----
        unsigned int*       cnt8  = (unsigned int*)ws;                      // 128 KB @ 0
        unsigned long long* pos64 = (unsigned long long*)(ws + (1u << 20)); // 4 MB  @ 1
        unsigned long long* stat  = (unsigned long long*)(ws + (5u << 20)); // 12.6  @ 5
        uint3*              rec0  = (uint3*)(ws + (18u << 20));             // 3 MB  @ 18
        uint3*              rec1  = (uint3*)(ws + (21u << 20));             // 3 MB  @ 21

        hipMemsetAsync(cnt8, 0, (size_t)(n_chk / 8) * 4, stream);
        build_a<<<(n + 255) / 256, 256, 0, stream>>>(edge_chk, cnt8, pos64, n);
        build_stat<<<chunks * NRANGE, 256, 0, stream>>>(pos64, stat, n, n_chk);
        for (int t = 0; t < T; ++t) {
            uint3* wr = (t & 1) ? rec1 : rec0;
            uint3* rd = (t & 1) ? rec0 : rec1;   // unused at t=0
            fused_check<<<(n_chk + 255) / 256, 256, 0, stream>>>(
                stat, llr, rd, wr, beta, alpha, t, n_chk, (t == 0) ? 1 : 0);
        }
        uint3* rec_fin = ((T - 1) & 1) ? rec1 : rec0;
        final_kernel<<<(n / 2 + 255) / 256, 256, 0, stream>>>(
            rec_fin, pos64, llr, (float*)d_out, n / 2, n);
    } else {
        // ---- fallback: verified split pipeline (16 MB, 368.8 us) ----
        unsigned int*       cnt8  = (unsigned int*)ws;                      // 128 KB @ 0
        unsigned long long* pos64 = (unsigned long long*)(ws + (1u << 20)); // 4 MB @ 1
        int*                vmap  = (int*)(ws + (5u << 20));                // 6 MB @ 5
        uint3*              recs  = (uint3*)(ws + (11u << 20));             // 3 MB @ 11
        float*              p     = (float*)(ws + (14u << 20));             // 2 MB @ 14

        hipMemsetAsync(cnt8, 0, (size_t)(n_chk / 8) * 4, stream);
        build_a<<<(n + 255) / 256, 256, 0, stream>>>(edge_chk, cnt8, pos64, n);
        build_b<<<chunks * NRANGE, 256, 0, stream>>>(pos64, vmap, n, E);
        for (int t = 0; t < T; ++t) {
            const float* src = (t == 0) ? llr : p;
            check_kernel<<<(n_chk + 255) / 256, 256, 0, stream>>>(
                src, vmap, recs, beta, alpha, t, n_chk, (t == 0) ? 1 : 0);
            if (t + 1 < T) {
                var_kernel<<<(n / 2 + 255) / 256, 256, 0, stream>>>(
                    recs, pos64, llr, p, n / 2);
            } else {
                final_kernel<<<(n / 2 + 255) / 256, 256, 0, stream>>>(
                    recs, pos64, llr, (float*)d_out, n / 2, n);
            }
        }
    }
}